// Round 3
// baseline (1153.718 us; speedup 1.0000x reference)
//
#include <hip/hip_runtime.h>
#include <hip/hip_bf16.h>
#include <stdint.h>

#define Bn 32
#define Ln 2048
#define Dn 64

typedef __bf16 bf16x8_t __attribute__((ext_vector_type(8)));
typedef float f32x4_t __attribute__((ext_vector_type(4)));

// ushort index into a [rows][64]-bf16 tile (128 B rows), XOR-swizzled (T2 / G4)
__device__ __forceinline__ int swzi(int row, int col) {
  return (((row << 7) + (col << 1)) ^ ((row & 7) << 4)) >> 1;
}

// mask-bit LDS index: [64 w32-words][64 rows] u32, row XOR-swizzled so packing
// writes (w32 = lane) spread 2-way over banks and reads broadcast per 16-lane group.
__device__ __forceinline__ int bidx(int w32, int row) {
  return (w32 << 6) | (row ^ (w32 & 31));
}

// ---- K/Q tile staging, split into issue-early load and write-late finish (T14) ----
struct TileRegs { float4 a0, b0, a1, b1; };

__device__ __forceinline__ void load_tile(const float* __restrict__ src, int tid, TileRegs& t) {
  {
    const int row = tid >> 3, h = tid & 7;
    const float4* p = (const float4*)(src + row * 64 + h * 8);
    t.a0 = p[0]; t.b0 = p[1];
  }
  {
    const int chunk = 256 + tid;
    const int row = chunk >> 3, h = chunk & 7;
    const float4* p = (const float4*)(src + row * 64 + h * 8);
    t.a1 = p[0]; t.b1 = p[1];
  }
}

__device__ __forceinline__ void finish_half(float4 x0, float4 x1, __bf16* dst, int row, int h) {
  float ss = x0.x * x0.x + x0.y * x0.y + x0.z * x0.z + x0.w * x0.w +
             x1.x * x1.x + x1.y * x1.y + x1.z * x1.z + x1.w * x1.w;
  ss += __shfl_xor(ss, 1);
  ss += __shfl_xor(ss, 2);
  ss += __shfl_xor(ss, 4);
  const float inv = 1.0f / fmaxf(sqrtf(ss), 1e-12f);
  bf16x8_t hv;
  hv[0] = (__bf16)(x0.x * inv); hv[1] = (__bf16)(x0.y * inv);
  hv[2] = (__bf16)(x0.z * inv); hv[3] = (__bf16)(x0.w * inv);
  hv[4] = (__bf16)(x1.x * inv); hv[5] = (__bf16)(x1.y * inv);
  hv[6] = (__bf16)(x1.z * inv); hv[7] = (__bf16)(x1.w * inv);
  *(bf16x8_t*)&dst[swzi(row, h * 8)] = hv;
}

__device__ __forceinline__ void finish_tile(const TileRegs& t, __bf16* dst, int tid) {
  finish_half(t.a0, t.b0, dst, tid >> 3, tid & 7);
  const int chunk = 256 + tid;
  finish_half(t.a1, t.b1, dst, chunk >> 3, chunk & 7);
}

// ---- V tile: load raw, finish writes transposed bf16 [feat][key] swizzled ----
struct VRegs { float4 y0, y1, y2, y3; };

__device__ __forceinline__ void load_v(const float* __restrict__ src, int tid, VRegs& v) {
  const int krow = tid >> 2, seg = tid & 3;
  const float4* p = (const float4*)(src + krow * 64) + seg * 4;
  v.y0 = p[0]; v.y1 = p[1]; v.y2 = p[2]; v.y3 = p[3];
}

__device__ __forceinline__ void finish_v(const VRegs& v, __bf16* dst, int tid) {
  const int krow = tid >> 2, seg = tid & 3;
  const float4 ys[4] = {v.y0, v.y1, v.y2, v.y3};
#pragma unroll
  for (int j = 0; j < 4; ++j) {
    const float4 x = ys[j];
    const int f = seg * 16 + j * 4;
    dst[swzi(f + 0, krow)] = (__bf16)x.x;
    dst[swzi(f + 1, krow)] = (__bf16)x.y;
    dst[swzi(f + 2, krow)] = (__bf16)x.z;
    dst[swzi(f + 3, krow)] = (__bf16)x.w;
  }
}

__global__ __launch_bounds__(256, 4)
void cosattn_kernel(const float* __restrict__ q, const float* __restrict__ kk,
                    const float* __restrict__ v, const int* __restrict__ mask,
                    float* __restrict__ out, float* __restrict__ attn) {
  __shared__ __align__(16) __bf16 KN[2][4096];  // Kn dbuf (16 KB); idle buf hosts per-wave S
  __shared__ __align__(16) __bf16 VT[4096];     // Q-stage at start, V^T in pass 2 (8 KB)
  __shared__ unsigned BITS32[4096];             // mask bits [w32][row] swizzled (16 KB)
  // total LDS = 40960 B -> 4 WG/CU

  const int tid = threadIdx.x;
  const int wid = tid >> 6;
  const int lane = tid & 63;
  const int c = lane & 15;
  const int g = lane >> 4;

  // XCD-contiguous block swizzle (T1); 1024 % 8 == 0 -> bijective
  const int bid = blockIdx.x;
  const int flat = (bid & 7) * 128 + (bid >> 3);
  const int b = flat >> 5;
  const int qt = flat & 31;

  const float* qb = q + ((size_t)b * Ln + (size_t)qt * 64) * Dn;
  const float* kb = kk + (size_t)b * Ln * Dn;
  const float* vb = v + (size_t)b * Ln * Dn;
  const int* mb = mask + (size_t)b * Ln * Ln + (size_t)qt * 64 * Ln;
  float* attnb = attn + (size_t)b * Ln * Ln;

  // ---- Prologue: issue Q + K0 loads, pack mask bits, then finish Q/K0 into LDS ----
  TileRegs qr, kr;
  load_tile(qb, tid, qr);
  load_tile(kb, tid, kr);

#pragma unroll 2
  for (int it = 0; it < 16; ++it) {
    const int f = it * 256 + tid;                    // 0..4095 = qrow*64 + w32
    const int qrow = f >> 6, w32 = f & 63;
    const uint4* p = (const uint4*)(mb + qrow * 2048 + w32 * 32);  // 128 B contiguous
    unsigned m = 0;
#pragma unroll
    for (int j = 0; j < 8; ++j) {
      uint4 x = p[j];
      m |= ((x.x & 1u) | ((x.y & 1u) << 1) | ((x.z & 1u) << 2) | ((x.w & 1u) << 3)) << (j * 4);
    }
    BITS32[bidx(w32, qrow)] = m;
  }

  finish_tile(qr, VT, tid);
  finish_tile(kr, KN[0], tid);
  __syncthreads();

  // Q A-fragments held in VGPRs for the whole kernel.
  bf16x8_t a0 = *(const bf16x8_t*)&VT[swzi(wid * 16 + c, g * 8)];
  bf16x8_t a1 = *(const bf16x8_t*)&VT[swzi(wid * 16 + c, 32 + g * 8)];

  // ---- Pass 1: row sums of masked (cos+1); K double-buffered with reg prefetch ----
  float rsum[4] = {0.f, 0.f, 0.f, 0.f};
  for (int kt = 0; kt < 32; ++kt) {
    const int cur = kt & 1;
    if (kt < 31) load_tile(kb + (kt + 1) * 4096, tid, kr);  // issue early
    const __bf16* KC = KN[cur];
    unsigned mr[4][2];
#pragma unroll
    for (int r = 0; r < 4; ++r) {
      const int qrl = wid * 16 + g * 4 + r;
      mr[r][0] = BITS32[bidx(2 * kt, qrl)];
      mr[r][1] = BITS32[bidx(2 * kt + 1, qrl)];
    }
#pragma unroll
    for (int ct = 0; ct < 4; ++ct) {
      bf16x8_t b0 = *(const bf16x8_t*)&KC[swzi(ct * 16 + c, g * 8)];
      bf16x8_t b1 = *(const bf16x8_t*)&KC[swzi(ct * 16 + c, 32 + g * 8)];
      f32x4_t acc = {0.f, 0.f, 0.f, 0.f};
      acc = __builtin_amdgcn_mfma_f32_16x16x32_bf16(a0, b0, acc, 0, 0, 0);
      acc = __builtin_amdgcn_mfma_f32_16x16x32_bf16(a1, b1, acc, 0, 0, 0);
#pragma unroll
      for (int r = 0; r < 4; ++r) {
        const unsigned bit = (mr[r][ct >> 1] >> (((ct & 1) << 4) + c)) & 1u;
        rsum[r] += bit ? 0.f : (acc[r] + 1.f);
      }
    }
    __syncthreads();                    // readers of KN[cur] done
    if (kt < 31) {
      finish_tile(kr, KN[cur ^ 1], tid);
      __syncthreads();                  // writers of KN[cur^1] done
    }
  }

  float invr[4];
#pragma unroll
  for (int r = 0; r < 4; ++r) {
    float s = rsum[r];
    s += __shfl_xor(s, 1); s += __shfl_xor(s, 2);
    s += __shfl_xor(s, 4); s += __shfl_xor(s, 8);
    invr[r] = 1.0f / fmaxf(s, 1e-12f);
  }

  // ---- Pass 2 prologue: restage K0 + V0 (VT freed; a0/a1 live in regs) ----
  VRegs vr;
  load_tile(kb, tid, kr);
  load_v(vb, tid, vr);
  finish_tile(kr, KN[0], tid);
  finish_v(vr, VT, tid);
  __syncthreads();

  // ---- Pass 2: recompute scores, write normalized attn, MFMA PV ----
  f32x4_t oacc[4] = {{0.f,0.f,0.f,0.f},{0.f,0.f,0.f,0.f},{0.f,0.f,0.f,0.f},{0.f,0.f,0.f,0.f}};
  for (int kt = 0; kt < 32; ++kt) {
    const int cur = kt & 1;
    if (kt < 31) {
      load_tile(kb + (kt + 1) * 4096, tid, kr);  // issue early
      load_v(vb + (kt + 1) * 4096, tid, vr);
    }
    const __bf16* KC = KN[cur];
    __bf16* SL = (__bf16*)KN[cur ^ 1] + wid * 1024;  // wave-private S in the idle K buffer
    unsigned mr[4][2];
#pragma unroll
    for (int r = 0; r < 4; ++r) {
      const int qrl = wid * 16 + g * 4 + r;
      mr[r][0] = BITS32[bidx(2 * kt, qrl)];
      mr[r][1] = BITS32[bidx(2 * kt + 1, qrl)];
    }
#pragma unroll
    for (int ct = 0; ct < 4; ++ct) {
      bf16x8_t b0 = *(const bf16x8_t*)&KC[swzi(ct * 16 + c, g * 8)];
      bf16x8_t b1 = *(const bf16x8_t*)&KC[swzi(ct * 16 + c, 32 + g * 8)];
      f32x4_t acc = {0.f, 0.f, 0.f, 0.f};
      acc = __builtin_amdgcn_mfma_f32_16x16x32_bf16(a0, b0, acc, 0, 0, 0);
      acc = __builtin_amdgcn_mfma_f32_16x16x32_bf16(a1, b1, acc, 0, 0, 0);
#pragma unroll
      for (int r = 0; r < 4; ++r) {
        const int qrl = wid * 16 + g * 4 + r;
        const unsigned bit = (mr[r][ct >> 1] >> (((ct & 1) << 4) + c)) & 1u;
        const float s = bit ? 0.f : (acc[r] + 1.f);
        const float av = s * invr[r];
        attnb[(size_t)(qt * 64 + qrl) * Ln + kt * 64 + ct * 16 + c] = av;
        SL[swzi(g * 4 + r, ct * 16 + c)] = (__bf16)av;  // wave-private: no barrier needed
      }
    }
    bf16x8_t sa0 = *(const bf16x8_t*)&SL[swzi(c, g * 8)];
    bf16x8_t sa1 = *(const bf16x8_t*)&SL[swzi(c, 32 + g * 8)];
#pragma unroll
    for (int nt = 0; nt < 4; ++nt) {
      bf16x8_t vb0 = *(const bf16x8_t*)&VT[swzi(nt * 16 + c, g * 8)];
      bf16x8_t vb1 = *(const bf16x8_t*)&VT[swzi(nt * 16 + c, 32 + g * 8)];
      oacc[nt] = __builtin_amdgcn_mfma_f32_16x16x32_bf16(sa0, vb0, oacc[nt], 0, 0, 0);
      oacc[nt] = __builtin_amdgcn_mfma_f32_16x16x32_bf16(sa1, vb1, oacc[nt], 0, 0, 0);
    }
    __syncthreads();                    // readers of KN[cur]/VT done; S dead
    if (kt < 31) {
      finish_tile(kr, KN[cur ^ 1], tid);  // overwrites S region (dead)
      finish_v(vr, VT, tid);
      __syncthreads();
    }
  }

  // ---- Epilogue: write O ----
  float* ob = out + ((size_t)b * Ln + (size_t)qt * 64) * Dn;
#pragma unroll
  for (int nt = 0; nt < 4; ++nt)
#pragma unroll
    for (int r = 0; r < 4; ++r)
      ob[(wid * 16 + g * 4 + r) * 64 + nt * 16 + c] = oacc[nt][r];
}

extern "C" void kernel_launch(void* const* d_in, const int* in_sizes, int n_in,
                              void* d_out, int out_size, void* d_ws, size_t ws_size,
                              hipStream_t stream) {
  const float* q = (const float*)d_in[0];
  const float* k = (const float*)d_in[1];
  const float* v = (const float*)d_in[2];
  const int* mask = (const int*)d_in[3];
  float* out = (float*)d_out;
  float* attn = out + (size_t)Bn * Ln * Dn;  // tuple: (output, attn) flat-concat
  dim3 grid(Bn * (Ln / 64));
  cosattn_kernel<<<grid, 256, 0, stream>>>(q, k, v, mask, out, attn);
}